// Round 6
// baseline (876.238 us; speedup 1.0000x reference)
//
#include <hip/hip_runtime.h>
#include <hip/hip_cooperative_groups.h>
#include <math.h>

namespace cg = cooperative_groups;

#define FLAT 12288
#define NH   4096
#define KSTEPS 4
#define LRC 0.01f
#define WSCALE 64.0f
#define WINV   0.015625f

#define NBLK 256
#define TPB  512
#define ROWS_PER_BLK 48     // FLAT / NBLK
#define ROWS_PER_WAVE 6     // 48 / 8 waves
#define NSEGP NBLK          // partials segments

typedef float v2f __attribute__((ext_vector_type(2)));

__device__ __forceinline__ float sigm(float x) {
    return __builtin_amdgcn_rcpf(1.0f + __expf(-x));
}

template <int CTRL>
__device__ __forceinline__ float dpp_add(float x) {
    int s = __builtin_amdgcn_update_dpp(0, __float_as_int(x), CTRL, 0xf, 0xf, true);
    return x + __int_as_float(s);
}
__device__ __forceinline__ float wave_sum63(float x) {
    x = dpp_add<0x111>(x);
    x = dpp_add<0x112>(x);
    x = dpp_add<0x114>(x);
    x = dpp_add<0x118>(x);
    x = dpp_add<0x142>(x);  // row_bcast:15
    x = dpp_add<0x143>(x);  // row_bcast:31
    return x;               // lane 63 holds the full sum
}

// dot of this lane's 64 cols: wq[4] (16 fp8 each) against hreg[16] (float4)
__device__ __forceinline__ float dot64(const uint4* wq, const float4* hreg) {
    float d0 = 0.f, d1 = 0.f, d2 = 0.f, d3 = 0.f;
#pragma unroll
    for (int j = 0; j < 4; j++) {
        v2f f;
        f = __builtin_amdgcn_cvt_pk_f32_fp8(wq[j].x, false); d0 = fmaf(f.x, hreg[4*j+0].x, d0); d1 = fmaf(f.y, hreg[4*j+0].y, d1);
        f = __builtin_amdgcn_cvt_pk_f32_fp8(wq[j].x, true);  d2 = fmaf(f.x, hreg[4*j+0].z, d2); d3 = fmaf(f.y, hreg[4*j+0].w, d3);
        f = __builtin_amdgcn_cvt_pk_f32_fp8(wq[j].y, false); d0 = fmaf(f.x, hreg[4*j+1].x, d0); d1 = fmaf(f.y, hreg[4*j+1].y, d1);
        f = __builtin_amdgcn_cvt_pk_f32_fp8(wq[j].y, true);  d2 = fmaf(f.x, hreg[4*j+1].z, d2); d3 = fmaf(f.y, hreg[4*j+1].w, d3);
        f = __builtin_amdgcn_cvt_pk_f32_fp8(wq[j].z, false); d0 = fmaf(f.x, hreg[4*j+2].x, d0); d1 = fmaf(f.y, hreg[4*j+2].y, d1);
        f = __builtin_amdgcn_cvt_pk_f32_fp8(wq[j].z, true);  d2 = fmaf(f.x, hreg[4*j+2].z, d2); d3 = fmaf(f.y, hreg[4*j+2].w, d3);
        f = __builtin_amdgcn_cvt_pk_f32_fp8(wq[j].w, false); d0 = fmaf(f.x, hreg[4*j+3].x, d0); d1 = fmaf(f.y, hreg[4*j+3].y, d1);
        f = __builtin_amdgcn_cvt_pk_f32_fp8(wq[j].w, true);  d2 = fmaf(f.x, hreg[4*j+3].z, d2); d3 = fmaf(f.y, hreg[4*j+3].w, d3);
    }
    return (d0 + d1) + (d2 + d3);
}

// pacc[64] += unpack(wq) * vs
__device__ __forceinline__ void pacc64(const uint4* wq, float vs, float* pacc) {
#pragma unroll
    for (int j = 0; j < 4; j++) {
        v2f f;
        f = __builtin_amdgcn_cvt_pk_f32_fp8(wq[j].x, false); pacc[16*j+0]  = fmaf(f.x, vs, pacc[16*j+0]);  pacc[16*j+1]  = fmaf(f.y, vs, pacc[16*j+1]);
        f = __builtin_amdgcn_cvt_pk_f32_fp8(wq[j].x, true);  pacc[16*j+2]  = fmaf(f.x, vs, pacc[16*j+2]);  pacc[16*j+3]  = fmaf(f.y, vs, pacc[16*j+3]);
        f = __builtin_amdgcn_cvt_pk_f32_fp8(wq[j].y, false); pacc[16*j+4]  = fmaf(f.x, vs, pacc[16*j+4]);  pacc[16*j+5]  = fmaf(f.y, vs, pacc[16*j+5]);
        f = __builtin_amdgcn_cvt_pk_f32_fp8(wq[j].y, true);  pacc[16*j+6]  = fmaf(f.x, vs, pacc[16*j+6]);  pacc[16*j+7]  = fmaf(f.y, vs, pacc[16*j+7]);
        f = __builtin_amdgcn_cvt_pk_f32_fp8(wq[j].z, false); pacc[16*j+8]  = fmaf(f.x, vs, pacc[16*j+8]);  pacc[16*j+9]  = fmaf(f.y, vs, pacc[16*j+9]);
        f = __builtin_amdgcn_cvt_pk_f32_fp8(wq[j].z, true);  pacc[16*j+10] = fmaf(f.x, vs, pacc[16*j+10]); pacc[16*j+11] = fmaf(f.y, vs, pacc[16*j+11]);
        f = __builtin_amdgcn_cvt_pk_f32_fp8(wq[j].w, false); pacc[16*j+12] = fmaf(f.x, vs, pacc[16*j+12]); pacc[16*j+13] = fmaf(f.y, vs, pacc[16*j+13]);
        f = __builtin_amdgcn_cvt_pk_f32_fp8(wq[j].w, true);  pacc[16*j+14] = fmaf(f.x, vs, pacc[16*j+14]); pacc[16*j+15] = fmaf(f.y, vs, pacc[16*j+15]);
    }
}

#define RVB (FLAT / TPB)   // 24
#define RHB (NH / TPB)     // 8

__global__ __launch_bounds__(TPB) void k_all(const float* __restrict__ inputs,
                                             const float* __restrict__ W,
                                             const float* __restrict__ a_in,
                                             const float* __restrict__ b_in,
                                             float* __restrict__ out,
                                             unsigned int* __restrict__ W8,
                                             float* __restrict__ partials,
                                             float* __restrict__ h,
                                             float* __restrict__ hi,
                                             float* __restrict__ v) {
    cg::grid_group grid = cg::this_grid();
    const int t = threadIdx.x, b = blockIdx.x;
    const int lane = t & 63, wv = t >> 6;

    __shared__ float  lred[NH];       // 16 KiB: per-block column partial staging
    __shared__ float  hred[16][33];
    __shared__ float2 redB[2][8];

    // ---------- pass 0: h1 partials from fp32 W + convert W -> fp8 ----------
    {
        const float4* W4 = (const float4*)W;
        const int r0 = b * ROWS_PER_BLK;
        float4 acc0 = make_float4(0.f, 0.f, 0.f, 0.f);
        float4 acc1 = make_float4(0.f, 0.f, 0.f, 0.f);
        for (int r = r0; r < r0 + ROWS_PER_BLK; ++r) {
            float vr = inputs[r];
            float4 w0 = W4[(size_t)r * (NH / 4) + t];
            float4 w1 = W4[(size_t)r * (NH / 4) + t + TPB];
            acc0.x = fmaf(w0.x, vr, acc0.x); acc0.y = fmaf(w0.y, vr, acc0.y);
            acc0.z = fmaf(w0.z, vr, acc0.z); acc0.w = fmaf(w0.w, vr, acc0.w);
            acc1.x = fmaf(w1.x, vr, acc1.x); acc1.y = fmaf(w1.y, vr, acc1.y);
            acc1.z = fmaf(w1.z, vr, acc1.z); acc1.w = fmaf(w1.w, vr, acc1.w);
            unsigned int p0 = 0, p1 = 0;
            p0 = __builtin_amdgcn_cvt_pk_fp8_f32(w0.x * WSCALE, w0.y * WSCALE, p0, false);
            p0 = __builtin_amdgcn_cvt_pk_fp8_f32(w0.z * WSCALE, w0.w * WSCALE, p0, true);
            p1 = __builtin_amdgcn_cvt_pk_fp8_f32(w1.x * WSCALE, w1.y * WSCALE, p1, false);
            p1 = __builtin_amdgcn_cvt_pk_fp8_f32(w1.z * WSCALE, w1.w * WSCALE, p1, true);
            W8[(size_t)r * (NH / 4) + t]       = p0;
            W8[(size_t)r * (NH / 4) + t + TPB] = p1;
        }
        float4* P = (float4*)(partials + (size_t)b * NH);
        P[t] = acc0;
        P[t + TPB] = acc1;
    }
    grid.sync();

    // ---------- Gibbs loop ----------
    for (int step = 0; step < KSTEPS; ++step) {
        // h-reduce: block b owns 16 cols
        {
            int colg = t >> 5, s = t & 31;
            int col = b * 16 + colg;
            float sum = 0.f;
            for (int g = s; g < NSEGP; g += 32) sum += partials[(size_t)g * NH + col];
            hred[colg][s] = sum;
            __syncthreads();
            if (t < 16) {
                int col2 = b * 16 + t;
                float s2 = 0.f;
#pragma unroll
                for (int q = 0; q < 32; q++) s2 += hred[t][q];
                float hh = sigm(s2 + b_in[col2]);
                h[col2] = hh;
                if (step == 0) hi[col2] = hh;
            }
            __syncthreads();
        }
        grid.sync();

        const bool last = (step == KSTEPS - 1);

        // fused v-step (+ partials for next h unless last)
        {
            if (!last) {
                for (int i = t; i < NH; i += TPB) lred[i] = 0.f;
            }
            const float4* h4 = (const float4*)h;
            float4 hreg[16];
#pragma unroll
            for (int j = 0; j < 4; j++)
#pragma unroll
                for (int q = 0; q < 4; q++) hreg[4*j+q] = h4[4 * (lane + 64*j) + q];

            if (!last) __syncthreads();

            const uint4* W84 = (const uint4*)W8;
            const int rbase = b * ROWS_PER_BLK + wv * ROWS_PER_WAVE;
            float pacc[64];
#pragma unroll
            for (int i = 0; i < 64; i++) pacc[i] = 0.f;

            for (int i = 0; i < ROWS_PER_WAVE; i += 2) {
                int ra = rbase + i, rb = ra + 1;
                uint4 wqa[4], wqb[4];
#pragma unroll
                for (int j = 0; j < 4; j++) {
                    wqa[j] = W84[(size_t)ra * 256 + lane + 64*j];
                    wqb[j] = W84[(size_t)rb * 256 + lane + 64*j];
                }
                float da = wave_sum63(dot64(wqa, hreg));
                float db = wave_sum63(dot64(wqb, hreg));
                float fa = __shfl(da, 63), fb = __shfl(db, 63);
                float va = sigm(a_in[ra] + fa * WINV);
                float vb = sigm(a_in[rb] + fb * WINV);
                if (lane == 63) { v[ra] = va; v[rb] = vb; }
                if (!last) {
                    pacc64(wqa, va * WINV, pacc);
                    pacc64(wqb, vb * WINV, pacc);
                }
            }

            if (!last) {
#pragma unroll
                for (int j = 0; j < 4; j++)
#pragma unroll
                    for (int e = 0; e < 16; e++)
                        atomicAdd(&lred[16 * (lane + 64*j) + e], pacc[16*j + e]);
                __syncthreads();
                float4* P = (float4*)(partials + (size_t)b * NH);
                float4* L = (float4*)lred;
                P[2*t]   = L[2*t];
                P[2*t+1] = L[2*t+1];
                __syncthreads();
            }
        }
        grid.sync();
    }

    // ---------- phase B: samples 1..15 with rank-2 W (block 0 only) ----------
    if (b != 0) return;
    {
        float Vi[RVB], Vk[RVB], vv[RVB];
        float Hi[RHB], Hk[RHB], hh_[RHB], hini[RHB];

#pragma unroll
        for (int r = 0; r < RVB; r++) { int i = r * TPB + t; Vi[r] = inputs[i]; Vk[r] = v[i]; }
#pragma unroll
        for (int r = 0; r < RHB; r++) { int j = r * TPB + t; Hi[r] = hi[j]; Hk[r] = h[j]; }

        int rc = 0;
        for (int s = 1; s < 16; ++s) {
            const float* vin = inputs + (size_t)s * FLAT;
#pragma unroll
            for (int r = 0; r < RVB; r++) vv[r] = vin[r * TPB + t];

            for (int k = 0; k < KSTEPS; ++k) {
                float px0 = 0.f, px1 = 0.f, py0 = 0.f, py1 = 0.f;
#pragma unroll
                for (int r = 0; r < RVB; r += 2) {
                    px0 = fmaf(Vi[r],   vv[r],   px0); py0 = fmaf(Vk[r],   vv[r],   py0);
                    px1 = fmaf(Vi[r+1], vv[r+1], px1); py1 = fmaf(Vk[r+1], vv[r+1], py1);
                }
                float px = wave_sum63(px0 + px1), py = wave_sum63(py0 + py1);
                if (lane == 63) { float2 w2; w2.x = px; w2.y = py; redB[rc & 1][wv] = w2; }
                __syncthreads();
                float al = 0.f, be = 0.f;
#pragma unroll
                for (int w = 0; w < 8; w++) { float2 w2 = redB[rc & 1][w]; al += w2.x; be += w2.y; }
                rc++;
                float ca = LRC * (1.f + al), cb = LRC * (1.f + be);

                float qx = 0.f, qy = 0.f;
#pragma unroll
                for (int r = 0; r < RHB; r++) {
                    float hh = sigm(ca * Hi[r] - cb * Hk[r]);
                    hh_[r] = hh;
                    if (k == 0) hini[r] = hh;
                    qx = fmaf(Hi[r], hh, qx); qy = fmaf(Hk[r], hh, qy);
                }
                qx = wave_sum63(qx); qy = wave_sum63(qy);
                if (lane == 63) { float2 w2; w2.x = qx; w2.y = qy; redB[rc & 1][wv] = w2; }
                __syncthreads();
                float ga = 0.f, de = 0.f;
#pragma unroll
                for (int w = 0; w < 8; w++) { float2 w2 = redB[rc & 1][w]; ga += w2.x; de += w2.y; }
                rc++;
                float cg = LRC * (1.f + ga), cd = LRC * (1.f + de);

#pragma unroll
                for (int r = 0; r < RVB; r++) vv[r] = sigm(cg * Vi[r] - cd * Vk[r]);
            }

#pragma unroll
            for (int r = 0; r < RVB; r++) { Vk[r] = vv[r]; Vi[r] = vin[r * TPB + t]; }
#pragma unroll
            for (int r = 0; r < RHB; r++) { Hk[r] = hh_[r]; Hi[r] = hini[r]; }
        }

#pragma unroll
        for (int r = 0; r < RVB; r++) out[r * TPB + t] = Vk[r];
    }
}

// ================= launch =================

extern "C" void kernel_launch(void* const* d_in, const int* in_sizes, int n_in,
                              void* d_out, int out_size, void* d_ws, size_t ws_size,
                              hipStream_t stream) {
    const float* inputs = (const float*)d_in[0];
    const float* W      = (const float*)d_in[1];
    const float* a_in   = (const float*)d_in[2];
    const float* b_in   = (const float*)d_in[3];
    float* out = (float*)d_out;

    // ws: W8 (48 MiB) | partials (NSEGP*NH = 4 MiB) | h | hi | v
    unsigned int* W8 = (unsigned int*)d_ws;
    float* partials = (float*)((char*)d_ws + (size_t)FLAT * NH);
    float* h  = partials + (size_t)NSEGP * NH;
    float* hi = h + NH;
    float* v  = hi + NH;

    void* args[] = {(void*)&inputs, (void*)&W, (void*)&a_in, (void*)&b_in,
                    (void*)&out, (void*)&W8, (void*)&partials, (void*)&h,
                    (void*)&hi, (void*)&v};
    hipLaunchCooperativeKernel((void*)k_all, dim3(NBLK), dim3(TPB), args, 0, stream);
}

// Round 7
// 537.477 us; speedup vs baseline: 1.6303x; 1.6303x over previous
//
#include <hip/hip_runtime.h>
#include <math.h>

#define FLAT 12288
#define NH   4096
#define KSTEPS 4
#define LRC 0.01f
#define NSEG 384
#define RPS  32        // NSEG * RPS == FLAT
#define WSCALE 64.0f
#define WINV   0.015625f

typedef float v2f __attribute__((ext_vector_type(2)));

__device__ __forceinline__ float sigm(float x) {
    return __builtin_amdgcn_rcpf(1.0f + __expf(-x));
}

// ---- DPP wave64 sum: result valid in lane 63 ----
template <int CTRL>
__device__ __forceinline__ float dpp_add(float x) {
    int s = __builtin_amdgcn_update_dpp(0, __float_as_int(x), CTRL, 0xf, 0xf, true);
    return x + __int_as_float(s);
}
__device__ __forceinline__ float wave_sum63(float x) {
    x = dpp_add<0x111>(x);  // row_shr:1
    x = dpp_add<0x112>(x);  // row_shr:2
    x = dpp_add<0x114>(x);  // row_shr:4
    x = dpp_add<0x118>(x);  // row_shr:8
    x = dpp_add<0x142>(x);  // row_bcast:15
    x = dpp_add<0x143>(x);  // row_bcast:31
    return x;               // lane 63 holds the full sum
}

// ================= Phase A (identical to R4 best) =================

// Pass 0: read fp32 W, emit column partials for h1, convert W -> fp8 (x64).
// grid (4, NSEG), block 256; 4 cols/thread.
__global__ __launch_bounds__(256) void k_colpart_cvt(const float* __restrict__ W,
                                                     const float* __restrict__ v,
                                                     float* __restrict__ partials,
                                                     unsigned int* __restrict__ W8) {
    const float4* W4 = (const float4*)W;
    int c4 = blockIdx.x * 256 + threadIdx.x;           // [0,1024)
    int r0 = blockIdx.y * RPS;
    float4 acc = make_float4(0.f, 0.f, 0.f, 0.f);
    for (int r = r0; r < r0 + RPS; ++r) {
        float vr = v[r];
        float4 w = W4[(size_t)r * (NH / 4) + c4];
        acc.x = fmaf(w.x, vr, acc.x);
        acc.y = fmaf(w.y, vr, acc.y);
        acc.z = fmaf(w.z, vr, acc.z);
        acc.w = fmaf(w.w, vr, acc.w);
        unsigned int p = 0;
        p = __builtin_amdgcn_cvt_pk_fp8_f32(w.x * WSCALE, w.y * WSCALE, p, false);
        p = __builtin_amdgcn_cvt_pk_fp8_f32(w.z * WSCALE, w.w * WSCALE, p, true);
        W8[(size_t)r * (NH / 4) + c4] = p;
    }
    ((float4*)partials)[(size_t)blockIdx.y * (NH / 4) + c4] = acc;
}

// fp8 colpart: 16 cols/thread (uint4 = 16 fp8). grid NSEG, block 256.
__global__ __launch_bounds__(256) void k_colpart_fp8(const uint4* __restrict__ W8,
                                                     const float* __restrict__ v,
                                                     float* __restrict__ partials) {
    int c16 = threadIdx.x;                              // [0,256)
    int r0 = blockIdx.x * RPS;
    float acc[16];
#pragma unroll
    for (int i = 0; i < 16; i++) acc[i] = 0.f;
    for (int r = r0; r < r0 + RPS; ++r) {
        float vr = v[r] * WINV;                         // fold descale into v
        uint4 w = W8[(size_t)r * (NH / 16) + c16];
        v2f f;
        f = __builtin_amdgcn_cvt_pk_f32_fp8(w.x, false); acc[0]  = fmaf(f.x, vr, acc[0]);  acc[1]  = fmaf(f.y, vr, acc[1]);
        f = __builtin_amdgcn_cvt_pk_f32_fp8(w.x, true);  acc[2]  = fmaf(f.x, vr, acc[2]);  acc[3]  = fmaf(f.y, vr, acc[3]);
        f = __builtin_amdgcn_cvt_pk_f32_fp8(w.y, false); acc[4]  = fmaf(f.x, vr, acc[4]);  acc[5]  = fmaf(f.y, vr, acc[5]);
        f = __builtin_amdgcn_cvt_pk_f32_fp8(w.y, true);  acc[6]  = fmaf(f.x, vr, acc[6]);  acc[7]  = fmaf(f.y, vr, acc[7]);
        f = __builtin_amdgcn_cvt_pk_f32_fp8(w.z, false); acc[8]  = fmaf(f.x, vr, acc[8]);  acc[9]  = fmaf(f.y, vr, acc[9]);
        f = __builtin_amdgcn_cvt_pk_f32_fp8(w.z, true);  acc[10] = fmaf(f.x, vr, acc[10]); acc[11] = fmaf(f.y, vr, acc[11]);
        f = __builtin_amdgcn_cvt_pk_f32_fp8(w.w, false); acc[12] = fmaf(f.x, vr, acc[12]); acc[13] = fmaf(f.y, vr, acc[13]);
        f = __builtin_amdgcn_cvt_pk_f32_fp8(w.w, true);  acc[14] = fmaf(f.x, vr, acc[14]); acc[15] = fmaf(f.y, vr, acc[15]);
    }
    float4* P = (float4*)(partials + (size_t)blockIdx.x * NH + (size_t)c16 * 16);
#pragma unroll
    for (int q = 0; q < 4; q++) {
        float4 o; o.x = acc[4*q]; o.y = acc[4*q+1]; o.z = acc[4*q+2]; o.w = acc[4*q+3];
        P[q] = o;
    }
}

// h[col] = sigm(b + sum over nseg partials). grid NH/32, block 256 (32 cols x 8 seg-threads).
__global__ __launch_bounds__(256) void k_hreduce(const float* __restrict__ partials,
                                                 const float* __restrict__ b,
                                                 float* __restrict__ h,
                                                 float* __restrict__ hi,
                                                 int nseg) {
    int c  = threadIdx.x & 31;
    int sg = threadIdx.x >> 5;                          // 0..7
    int col = blockIdx.x * 32 + c;
    float s = 0.f;
    for (int g = sg; g < nseg; g += 8) s += partials[(size_t)g * NH + col];
    __shared__ float red[8][33];
    red[sg][c] = s;
    __syncthreads();
    if (threadIdx.x < 32) {
        float t = 0.f;
#pragma unroll
        for (int g2 = 0; g2 < 8; g2++) t += red[g2][threadIdx.x];
        float hh = sigm(t + b[col]);
        h[col] = hh;
        if (hi) hi[col] = hh;
    }
}

// v[row] = sigm(a + W8[row,:].h / 64). One wave per row. grid FLAT/4, block 256.
__global__ __launch_bounds__(256) void k_vstep_fp8(const unsigned char* __restrict__ W8,
                                                   const float* __restrict__ h,
                                                   const float* __restrict__ a,
                                                   float* __restrict__ v) {
    int wid = threadIdx.x >> 6, lane = threadIdx.x & 63;
    int row = blockIdx.x * 4 + wid;
    const uint4* Wr = (const uint4*)(W8 + (size_t)row * NH);
    const float4* h4 = (const float4*)h;
    float acc = 0.f;
    for (int k = lane; k < NH / 16; k += 64) {          // 4 iters
        uint4 w = Wr[k];
        float4 h0 = h4[4*k], h1 = h4[4*k+1], h2 = h4[4*k+2], h3 = h4[4*k+3];
        v2f f;
        f = __builtin_amdgcn_cvt_pk_f32_fp8(w.x, false); acc = fmaf(f.x, h0.x, acc); acc = fmaf(f.y, h0.y, acc);
        f = __builtin_amdgcn_cvt_pk_f32_fp8(w.x, true);  acc = fmaf(f.x, h0.z, acc); acc = fmaf(f.y, h0.w, acc);
        f = __builtin_amdgcn_cvt_pk_f32_fp8(w.y, false); acc = fmaf(f.x, h1.x, acc); acc = fmaf(f.y, h1.y, acc);
        f = __builtin_amdgcn_cvt_pk_f32_fp8(w.y, true);  acc = fmaf(f.x, h1.z, acc); acc = fmaf(f.y, h1.w, acc);
        f = __builtin_amdgcn_cvt_pk_f32_fp8(w.z, false); acc = fmaf(f.x, h2.x, acc); acc = fmaf(f.y, h2.y, acc);
        f = __builtin_amdgcn_cvt_pk_f32_fp8(w.z, true);  acc = fmaf(f.x, h2.z, acc); acc = fmaf(f.y, h2.w, acc);
        f = __builtin_amdgcn_cvt_pk_f32_fp8(w.w, false); acc = fmaf(f.x, h3.x, acc); acc = fmaf(f.y, h3.y, acc);
        f = __builtin_amdgcn_cvt_pk_f32_fp8(w.w, true);  acc = fmaf(f.x, h3.z, acc); acc = fmaf(f.y, h3.w, acc);
    }
    acc = wave_sum63(acc);
    if (lane == 63) v[row] = sigm(a[row] + acc * WINV);
}

// ================= Phase B (R4 + chain-split / LDS / register-reuse tweaks) =================

#define TB  512
#define RVB (FLAT / TB)   // 24
#define RHB (NH / TB)     // 8
#define NWAVES (TB / 64)  // 8

__global__ __launch_bounds__(512) void k_phaseB(const float* __restrict__ inputs,
                                                const float* __restrict__ hi0,
                                                const float* __restrict__ hk0,
                                                const float* __restrict__ vk0,
                                                float* __restrict__ out) {
    int t = threadIdx.x;
    int lane = t & 63, wid = t >> 6;
    __shared__ float2 red[2][NWAVES];   // 2 x 8 x float2 = contiguous 128 B

    float Vi[RVB], Vk[RVB], v[RVB], Vn[RVB];
    float Hi[RHB], Hk[RHB], h[RHB], hini[RHB];

#pragma unroll
    for (int r = 0; r < RVB; r++) { int i = r * TB + t; Vi[r] = inputs[i]; Vk[r] = vk0[i]; }
#pragma unroll
    for (int r = 0; r < RHB; r++) { int j = r * TB + t; Hi[r] = hi0[j]; Hk[r] = hk0[j]; }

    int rc = 0;
    for (int s = 1; s < 16; ++s) {
        const float* vin = inputs + (size_t)s * FLAT;
#pragma unroll
        for (int r = 0; r < RVB; r++) { Vn[r] = vin[r * TB + t]; v[r] = Vn[r]; }

        for (int k = 0; k < KSTEPS; ++k) {
            // alpha = Vi.v, beta = Vk.v   (4-way split chains: dep depth 6)
            float px0 = 0.f, px1 = 0.f, px2 = 0.f, px3 = 0.f;
            float py0 = 0.f, py1 = 0.f, py2 = 0.f, py3 = 0.f;
#pragma unroll
            for (int r = 0; r < RVB; r += 4) {
                px0 = fmaf(Vi[r],   v[r],   px0); py0 = fmaf(Vk[r],   v[r],   py0);
                px1 = fmaf(Vi[r+1], v[r+1], px1); py1 = fmaf(Vk[r+1], v[r+1], py1);
                px2 = fmaf(Vi[r+2], v[r+2], px2); py2 = fmaf(Vk[r+2], v[r+2], py2);
                px3 = fmaf(Vi[r+3], v[r+3], px3); py3 = fmaf(Vk[r+3], v[r+3], py3);
            }
            float px = wave_sum63((px0 + px1) + (px2 + px3));
            float py = wave_sum63((py0 + py1) + (py2 + py3));
            if (lane == 63) { float2 w2; w2.x = px; w2.y = py; red[rc & 1][wid] = w2; }
            __syncthreads();
            float al, be;
            {   // read 8 float2 as 4 float4 (fewer LDS ops on the critical path)
                const float4* R4 = (const float4*)&red[rc & 1][0];
                float4 r0 = R4[0], r1 = R4[1], r2 = R4[2], r3 = R4[3];
                al = (r0.x + r1.x) + (r2.x + r3.x) + ((r0.z + r1.z) + (r2.z + r3.z));
                be = (r0.y + r1.y) + (r2.y + r3.y) + ((r0.w + r1.w) + (r2.w + r3.w));
            }
            rc++;
            float ca = LRC * (1.f + al), cb = LRC * (1.f + be);

            // h = sigm(LR((1+al)Hi - (1+be)Hk)); gamma = Hi.h, delta = Hk.h
            float qx0 = 0.f, qx1 = 0.f, qy0 = 0.f, qy1 = 0.f;
#pragma unroll
            for (int r = 0; r < RHB; r += 2) {
                float h0 = sigm(ca * Hi[r]   - cb * Hk[r]);
                float h1 = sigm(ca * Hi[r+1] - cb * Hk[r+1]);
                h[r] = h0; h[r+1] = h1;
                if (k == 0) { hini[r] = h0; hini[r+1] = h1; }
                qx0 = fmaf(Hi[r],   h0, qx0); qy0 = fmaf(Hk[r],   h0, qy0);
                qx1 = fmaf(Hi[r+1], h1, qx1); qy1 = fmaf(Hk[r+1], h1, qy1);
            }
            float qx = wave_sum63(qx0 + qx1), qy = wave_sum63(qy0 + qy1);
            if (lane == 63) { float2 w2; w2.x = qx; w2.y = qy; red[rc & 1][wid] = w2; }
            __syncthreads();
            float ga, de;
            {
                const float4* R4 = (const float4*)&red[rc & 1][0];
                float4 r0 = R4[0], r1 = R4[1], r2 = R4[2], r3 = R4[3];
                ga = (r0.x + r1.x) + (r2.x + r3.x) + ((r0.z + r1.z) + (r2.z + r3.z));
                de = (r0.y + r1.y) + (r2.y + r3.y) + ((r0.w + r1.w) + (r2.w + r3.w));
            }
            rc++;
            float cg = LRC * (1.f + ga), cd = LRC * (1.f + de);

            // v = sigm(LR((1+ga)Vi - (1+de)Vk))
#pragma unroll
            for (int r = 0; r < RVB; r++) v[r] = sigm(cg * Vi[r] - cd * Vk[r]);
        }

        // rotate carry (Vi <- this sample's input, already in registers)
#pragma unroll
        for (int r = 0; r < RVB; r++) { Vk[r] = v[r]; Vi[r] = Vn[r]; }
#pragma unroll
        for (int r = 0; r < RHB; r++) { Hk[r] = h[r]; Hi[r] = hini[r]; }
    }

#pragma unroll
    for (int r = 0; r < RVB; r++) out[r * TB + t] = Vk[r];
}

// ================= launch =================

extern "C" void kernel_launch(void* const* d_in, const int* in_sizes, int n_in,
                              void* d_out, int out_size, void* d_ws, size_t ws_size,
                              hipStream_t stream) {
    const float* inputs = (const float*)d_in[0];
    const float* W      = (const float*)d_in[1];
    const float* a_in   = (const float*)d_in[2];
    const float* b_in   = (const float*)d_in[3];
    float* out = (float*)d_out;

    // ws layout: W8 (48 MiB) | partials (NSEG*NH = 6 MiB) | h | hi | v
    unsigned int* W8 = (unsigned int*)d_ws;
    float* partials = (float*)((char*)d_ws + (size_t)FLAT * NH);
    float* h  = partials + (size_t)NSEG * NH;
    float* hi = h + NH;
    float* v  = hi + NH;

    dim3 blk(256);

    // Sample 0, Gibbs step 1 (h1 == h_init) + W -> fp8 conversion
    k_colpart_cvt<<<dim3(4, NSEG), blk, 0, stream>>>(W, inputs, partials, W8);
    k_hreduce<<<dim3(NH / 32), blk, 0, stream>>>(partials, b_in, h, hi, NSEG);
    k_vstep_fp8<<<dim3(FLAT / 4), blk, 0, stream>>>((const unsigned char*)W8, h, a_in, v);

    // Gibbs steps 2..4
    for (int k = 1; k < KSTEPS; ++k) {
        k_colpart_fp8<<<dim3(NSEG), blk, 0, stream>>>((const uint4*)W8, v, partials);
        k_hreduce<<<dim3(NH / 32), blk, 0, stream>>>(partials, b_in, h, (float*)nullptr, NSEG);
        k_vstep_fp8<<<dim3(FLAT / 4), blk, 0, stream>>>((const unsigned char*)W8, h, a_in, v);
    }

    // Samples 1..15 (rank-2 W), writes final reconstruction
    k_phaseB<<<1, TB, 0, stream>>>(inputs, hi, h, v, out);
}